// Round 11
// baseline (245.802 us; speedup 1.0000x reference)
//
#include <hip/hip_runtime.h>
#include <hip/hip_bf16.h>
#include <cstdint>

#define B_  4
#define N_  4096
#define C_  256
#define CD_ 64

typedef unsigned short ushort_t;
typedef __bf16 bf16x8 __attribute__((ext_vector_type(8)));
typedef float f32x4 __attribute__((ext_vector_type(4)));

typedef const __attribute__((address_space(1))) void* gas_t;
typedef __attribute__((address_space(3))) void* las_t;

// (1/sqrt(256)) * log2(e): folded into K projection so S' = S_true * log2(e)
static constexpr float SCALE_LOG2E = 0.09016844005556021f;

__device__ __forceinline__ ushort_t f2bf(float x) {
    union { float f; unsigned u; } v; v.f = x;
    unsigned u = v.u;
    unsigned r = (u + 0x7fffu + ((u >> 16) & 1u)) >> 16;  // round-nearest-even
    return (ushort_t)r;
}

__device__ __forceinline__ bf16x8 ld_bf8(const ushort_t* p) {
    return *reinterpret_cast<const bf16x8*>(p);
}

// ---------------------------------------------------------------------------
// MFMA projection -> TRANSPOSED layout dst[b][n][o]  (proven R8)
// ---------------------------------------------------------------------------
__global__ __launch_bounds__(256, 4)
void proj_q_mfma(const float* __restrict__ X, const float* __restrict__ W,
                 const float* __restrict__ bias, ushort_t* __restrict__ dst,
                 int Cin, float outScale) {
    __shared__ ushort_t sX[128][72];   // [n][c] bf16
    __shared__ ushort_t sW[64][72];    // [o][c] bf16
    const int tid = threadIdx.x;
    const int lane = tid & 63, g = lane >> 4, c16 = lane & 15;
    const int w = tid >> 6, wi = w >> 1, wj = w & 1;   // n-half, o-half
    const int b = blockIdx.z, nb = blockIdx.x * 128, ob = blockIdx.y * 64;
    f32x4 acc[4][2];
#pragma unroll
    for (int nt = 0; nt < 4; ++nt)
#pragma unroll
        for (int ot = 0; ot < 2; ++ot) acc[nt][ot] = (f32x4){0.f, 0.f, 0.f, 0.f};

    const int cr = tid >> 5;          // staging: c-row within pass
    const int n0 = (tid & 31) * 4;    // staging: 4 n's

    for (int k0 = 0; k0 < Cin; k0 += 64) {
#pragma unroll
        for (int p = 0; p < 8; ++p) {
            const int c = p * 8 + cr;
            float4 xv = *(const float4*)(X + ((size_t)b * Cin + k0 + c) * N_ + nb + n0);
            sX[n0 + 0][c] = f2bf(xv.x);
            sX[n0 + 1][c] = f2bf(xv.y);
            sX[n0 + 2][c] = f2bf(xv.z);
            sX[n0 + 3][c] = f2bf(xv.w);
        }
        {
            const int o = tid >> 2, cq = (tid & 3) * 16;
            const float* wsrc = W + (size_t)(ob + o) * Cin + k0 + cq;
            alignas(16) ushort_t tmp[16];
#pragma unroll
            for (int q = 0; q < 16; ++q) tmp[q] = f2bf(wsrc[q]);
            *(uint4*)&sW[o][cq]     = *(uint4*)&tmp[0];
            *(uint4*)&sW[o][cq + 8] = *(uint4*)&tmp[8];
        }
        __syncthreads();
#pragma unroll
        for (int ks = 0; ks < 2; ++ks) {
            bf16x8 af[4], bfr[2];
#pragma unroll
            for (int nt = 0; nt < 4; ++nt)
                af[nt] = *(const bf16x8*)&sX[wi * 64 + nt * 16 + c16][ks * 32 + g * 8];
#pragma unroll
            for (int ot = 0; ot < 2; ++ot)
                bfr[ot] = *(const bf16x8*)&sW[wj * 32 + ot * 16 + c16][ks * 32 + g * 8];
#pragma unroll
            for (int nt = 0; nt < 4; ++nt)
#pragma unroll
                for (int ot = 0; ot < 2; ++ot)
                    acc[nt][ot] = __builtin_amdgcn_mfma_f32_16x16x32_bf16(af[nt], bfr[ot], acc[nt][ot], 0, 0, 0);
        }
        __syncthreads();
    }
#pragma unroll
    for (int ot = 0; ot < 2; ++ot) {
        const int o = ob + wj * 32 + ot * 16 + c16;
        const float bia = bias[o];
#pragma unroll
        for (int nt = 0; nt < 4; ++nt) {
#pragma unroll
            for (int r = 0; r < 4; ++r) {
                const int n = nb + wi * 64 + nt * 16 + g * 4 + r;
                dst[((size_t)b * N_ + n) * C_ + o] = f2bf((acc[nt][ot][r] + bia) * outScale);
            }
        }
    }
}

// ---------------------------------------------------------------------------
// Fused K+V MFMA projection from x_dem (proven R8)
// ---------------------------------------------------------------------------
__global__ __launch_bounds__(256, 4)
void proj_kv_mfma(const float* __restrict__ X, const float* __restrict__ Wk,
                  const float* __restrict__ bk, const float* __restrict__ Wv,
                  const float* __restrict__ bv, ushort_t* __restrict__ Kt,
                  ushort_t* __restrict__ Vm) {
    __shared__ ushort_t sX[128][72];   // [n][c]
    __shared__ ushort_t sWk[64][72];   // [o][c]
    __shared__ ushort_t sWv[64][72];
    const int tid = threadIdx.x;
    const int lane = tid & 63, g = lane >> 4, c16 = lane & 15;
    const int w = tid >> 6;
    const int b = blockIdx.z, nb = blockIdx.x * 128, ob = blockIdx.y * 64;

    {
        const int cr = tid >> 5, n0 = (tid & 31) * 4;
#pragma unroll
        for (int p = 0; p < 8; ++p) {
            const int c = p * 8 + cr;
            float4 xv = *(const float4*)(X + ((size_t)b * CD_ + c) * N_ + nb + n0);
            sX[n0 + 0][c] = f2bf(xv.x);
            sX[n0 + 1][c] = f2bf(xv.y);
            sX[n0 + 2][c] = f2bf(xv.z);
            sX[n0 + 3][c] = f2bf(xv.w);
        }
        const int o = tid >> 2, cq = (tid & 3) * 16;
        alignas(16) ushort_t tk[16], tv[16];
        const float* ksrc = Wk + (size_t)(ob + o) * CD_ + cq;
        const float* vsrc = Wv + (size_t)(ob + o) * CD_ + cq;
#pragma unroll
        for (int q = 0; q < 16; ++q) { tk[q] = f2bf(ksrc[q]); tv[q] = f2bf(vsrc[q]); }
        *(uint4*)&sWk[o][cq]     = *(uint4*)&tk[0];
        *(uint4*)&sWk[o][cq + 8] = *(uint4*)&tk[8];
        *(uint4*)&sWv[o][cq]     = *(uint4*)&tv[0];
        *(uint4*)&sWv[o][cq + 8] = *(uint4*)&tv[8];
    }
    __syncthreads();
    // ---- K-part ----
    {
        const int wi = w >> 1, wj = w & 1;
        f32x4 acc[4][2];
#pragma unroll
        for (int nt = 0; nt < 4; ++nt)
#pragma unroll
            for (int ot = 0; ot < 2; ++ot) acc[nt][ot] = (f32x4){0.f, 0.f, 0.f, 0.f};
#pragma unroll
        for (int ks = 0; ks < 2; ++ks) {
            bf16x8 af[4], bfr[2];
#pragma unroll
            for (int nt = 0; nt < 4; ++nt)
                af[nt] = *(const bf16x8*)&sX[wi * 64 + nt * 16 + c16][ks * 32 + g * 8];
#pragma unroll
            for (int ot = 0; ot < 2; ++ot)
                bfr[ot] = *(const bf16x8*)&sWk[wj * 32 + ot * 16 + c16][ks * 32 + g * 8];
#pragma unroll
            for (int nt = 0; nt < 4; ++nt)
#pragma unroll
                for (int ot = 0; ot < 2; ++ot)
                    acc[nt][ot] = __builtin_amdgcn_mfma_f32_16x16x32_bf16(af[nt], bfr[ot], acc[nt][ot], 0, 0, 0);
        }
#pragma unroll
        for (int ot = 0; ot < 2; ++ot) {
            const int o = ob + wj * 32 + ot * 16 + c16;
            const float bia = bk[o];
#pragma unroll
            for (int nt = 0; nt < 4; ++nt)
#pragma unroll
                for (int r = 0; r < 4; ++r) {
                    const int n = nb + wi * 64 + nt * 16 + g * 4 + r;
                    Kt[((size_t)b * N_ + n) * C_ + o] = f2bf((acc[nt][ot][r] + bia) * SCALE_LOG2E);
                }
        }
    }
    // ---- V-part ----
    {
        const int ow = w & 1, nw = w >> 1;
        f32x4 acc[2][4];
#pragma unroll
        for (int mt = 0; mt < 2; ++mt)
#pragma unroll
            for (int nt = 0; nt < 4; ++nt) acc[mt][nt] = (f32x4){0.f, 0.f, 0.f, 0.f};
#pragma unroll
        for (int ks = 0; ks < 2; ++ks) {
            bf16x8 af[2], bfr[4];
#pragma unroll
            for (int mt = 0; mt < 2; ++mt)
                af[mt] = *(const bf16x8*)&sWv[ow * 32 + mt * 16 + c16][ks * 32 + g * 8];
#pragma unroll
            for (int nt = 0; nt < 4; ++nt)
                bfr[nt] = *(const bf16x8*)&sX[nw * 64 + nt * 16 + c16][ks * 32 + g * 8];
#pragma unroll
            for (int mt = 0; mt < 2; ++mt)
#pragma unroll
                for (int nt = 0; nt < 4; ++nt)
                    acc[mt][nt] = __builtin_amdgcn_mfma_f32_16x16x32_bf16(af[mt], bfr[nt], acc[mt][nt], 0, 0, 0);
        }
#pragma unroll
        for (int mt = 0; mt < 2; ++mt) {
            const float4 bi4 = *(const float4*)(bv + ob + ow * 32 + mt * 16 + g * 4);
            const float bia[4] = {bi4.x, bi4.y, bi4.z, bi4.w};
#pragma unroll
            for (int nt = 0; nt < 4; ++nt) {
                const int n = nb + nw * 64 + nt * 16 + c16;
#pragma unroll
                for (int r = 0; r < 4; ++r) {
                    const int o = ob + ow * 32 + mt * 16 + g * 4 + r;
                    Vm[((size_t)b * C_ + o) * N_ + n] = f2bf(acc[mt][nt][r] + bia[r]);
                }
            }
        }
    }
}

// ---------------------------------------------------------------------------
// Pass A (R6 structure, (256,4)).
// ---------------------------------------------------------------------------
__global__ __launch_bounds__(256, 4)
void stats_kernel(const ushort_t* __restrict__ Kt, const ushort_t* __restrict__ Qt,
                  float* __restrict__ l, ushort_t* __restrict__ PT) {
    __shared__ ushort_t smem[17408];
    const int tid = threadIdx.x;
    const int lane = tid & 63, g = lane >> 4, c16 = lane & 15;
    const int w = tid >> 6, wi = w >> 1, wj = w & 1;
    const int b = blockIdx.z;
    const int ib = blockIdx.y * 128, jb = blockIdx.x * 128;
    f32x4 acc[4][4];
#pragma unroll
    for (int mt = 0; mt < 4; ++mt)
#pragma unroll
        for (int nt = 0; nt < 4; ++nt) acc[mt][nt] = (f32x4){0.f, 0.f, 0.f, 0.f};

    const int srow = tid >> 3;
    const int sc4 = tid & 7;

    for (int k0 = 0; k0 < 256; k0 += 64) {
#pragma unroll
        for (int q = 0; q < 4; ++q) {
            const int row = q * 32 + srow;
            const int gc = sc4 ^ (row & 7);
            const ushort_t* srcA = Kt + ((size_t)(b * N_ + ib + row)) * C_ + k0 + gc * 8;
            const ushort_t* srcB = Qt + ((size_t)(b * N_ + jb + row)) * C_ + k0 + gc * 8;
            __builtin_amdgcn_global_load_lds((gas_t)srcA, (las_t)&smem[(q * 256 + tid) * 8], 16, 0, 0);
            __builtin_amdgcn_global_load_lds((gas_t)srcB, (las_t)&smem[8192 + (q * 256 + tid) * 8], 16, 0, 0);
        }
        __syncthreads();
#pragma unroll
        for (int ks = 0; ks < 2; ++ks) {
            bf16x8 af[4], bf[4];
#pragma unroll
            for (int mt = 0; mt < 4; ++mt) {
                const int row = wi * 64 + mt * 16 + c16;
                af[mt] = *(const bf16x8*)&smem[row * 64 + (((ks * 4 + g) ^ (row & 7)) * 8)];
            }
#pragma unroll
            for (int nt = 0; nt < 4; ++nt) {
                const int row = wj * 64 + nt * 16 + c16;
                bf[nt] = *(const bf16x8*)&smem[8192 + row * 64 + (((ks * 4 + g) ^ (row & 7)) * 8)];
            }
#pragma unroll
            for (int mt = 0; mt < 4; ++mt)
#pragma unroll
                for (int nt = 0; nt < 4; ++nt)
                    acc[mt][nt] = __builtin_amdgcn_mfma_f32_16x16x32_bf16(af[mt], bf[nt], acc[mt][nt], 0, 0, 0);
        }
        __syncthreads();
    }
#pragma unroll
    for (int mt = 0; mt < 4; ++mt) {
        float rs[4] = {0.f, 0.f, 0.f, 0.f};
#pragma unroll
        for (int nt = 0; nt < 4; ++nt) {
            float e0 = __builtin_amdgcn_exp2f(acc[mt][nt][0]);
            float e1 = __builtin_amdgcn_exp2f(acc[mt][nt][1]);
            float e2 = __builtin_amdgcn_exp2f(acc[mt][nt][2]);
            float e3 = __builtin_amdgcn_exp2f(acc[mt][nt][3]);
            rs[0] += e0; rs[1] += e1; rs[2] += e2; rs[3] += e3;
            if (PT != nullptr) {
                uint2 pk;
                pk.x = (unsigned)f2bf(e0) | ((unsigned)f2bf(e1) << 16);
                pk.y = (unsigned)f2bf(e2) | ((unsigned)f2bf(e3) << 16);
                const int jl = wj * 64 + nt * 16 + c16;
                const int il = wi * 64 + mt * 16 + g * 4;
                *(uint2*)&smem[jl * 136 + il] = pk;
            }
        }
#pragma unroll
        for (int r = 0; r < 4; ++r) {
            float s = rs[r];
            s += __shfl_xor(s, 1, 64);
            s += __shfl_xor(s, 2, 64);
            s += __shfl_xor(s, 4, 64);
            s += __shfl_xor(s, 8, 64);
            if (c16 == 0)
                atomicAdd(l + (size_t)b * N_ + ib + wi * 64 + mt * 16 + g * 4 + r, s);
        }
    }
    if (PT != nullptr) {
        __syncthreads();
        const int chb = tid & 15;
        const int rb = tid >> 4;
#pragma unroll
        for (int r = 0; r < 8; ++r) {
            const int jl = r * 16 + rb;
            uint4 v = *(const uint4*)&smem[jl * 136 + chb * 8];
            *(uint4*)(PT + ((size_t)(b * N_ + jb + jl)) * N_ + ib + chb * 8) = v;
        }
    }
}

// ---------------------------------------------------------------------------
// V' = V * rcp(l) elementwise.  (unchanged)
// ---------------------------------------------------------------------------
__global__ void scale_v_kernel(const ushort_t* __restrict__ Vm, const float* __restrict__ l,
                               ushort_t* __restrict__ Vs) {
    const int i = (blockIdx.x * 256 + threadIdx.x) * 8;
    const int c = blockIdx.y, b = blockIdx.z;
    float4 l0 = *(const float4*)(l + (size_t)b * N_ + i);
    float4 l1 = *(const float4*)(l + (size_t)b * N_ + i + 4);
    float r[8] = {__builtin_amdgcn_rcpf(l0.x), __builtin_amdgcn_rcpf(l0.y),
                  __builtin_amdgcn_rcpf(l0.z), __builtin_amdgcn_rcpf(l0.w),
                  __builtin_amdgcn_rcpf(l1.x), __builtin_amdgcn_rcpf(l1.y),
                  __builtin_amdgcn_rcpf(l1.z), __builtin_amdgcn_rcpf(l1.w)};
    const size_t off = ((size_t)(b * C_ + c)) * N_ + i;
    uint4 v = *(const uint4*)(Vm + off);
    unsigned vw[4] = {v.x, v.y, v.z, v.w};
    uint4 o;
    unsigned* ow = &o.x;
#pragma unroll
    for (int q = 0; q < 4; ++q) {
        union { unsigned u; float f; } lo, hi;
        lo.u = (vw[q] & 0xffffu) << 16;
        hi.u = vw[q] & 0xffff0000u;
        float f0 = lo.f * r[q * 2 + 0];
        float f1 = hi.f * r[q * 2 + 1];
        ow[q] = (unsigned)f2bf(f0) | ((unsigned)f2bf(f1) << 16);
    }
    *(uint4*)(Vs + off) = o;
}

// ---------------------------------------------------------------------------
// Pass B v7: single-K GEMM, no atomics, fused residual (R10 structure).
// R11: j-tile 64->32 -> grid 512 = 2 blocks/CU (R10 measured occupancy 20% =
// exactly 1 block/CU; 128 barriers/block each exposed the full ~900cyc vmcnt
// drain with no cross-block overlap).  LDS 36 KB -> 2 blocks fit; 8 waves x
// (32c x 32j), acc[2][2].  PT still read once per element; Vs re-reads are
// L3/L2-resident.
// ---------------------------------------------------------------------------
__global__ __launch_bounds__(512, 4)
void gemm_out2_kernel(const ushort_t* __restrict__ A /*Vs [B][C][N]*/,
                      const ushort_t* __restrict__ Bm /*PT [B][N][N]*/,
                      const float* __restrict__ R /*x_s2 as [B][C][N]*/,
                      float* __restrict__ out) {
    __shared__ ushort_t sA[256 * 64];   // 32 KB: rows c, 8 swizzled 16B chunks
    __shared__ ushort_t sB[32 * 64];    //  4 KB: rows j
    const int tid = threadIdx.x;
    const int lane = tid & 63, g = lane >> 4, c16 = lane & 15;
    const int w = tid >> 6;
    const int cw = w * 32;              // wave's 32-c band
    const int b = blockIdx.y;
    const int jb = blockIdx.x * 32;

    f32x4 acc[2][2];
#pragma unroll
    for (int mt = 0; mt < 2; ++mt)
#pragma unroll
        for (int nt = 0; nt < 2; ++nt) acc[mt][nt] = (f32x4){0.f, 0.f, 0.f, 0.f};

    const int sch = tid & 7;          // chunk slot within row

    for (int k0 = 0; k0 < 4096; k0 += 64) {
        // stage A (Vs): 256 rows x 8 chunks = 2048 slots, 4 passes
#pragma unroll
        for (int q = 0; q < 4; ++q) {
            const int slot = q * 512 + tid;
            const int row = slot >> 3;
            const int gc = sch ^ (row & 7);
            const ushort_t* src = A + ((size_t)(b * C_ + row)) * N_ + k0 + gc * 8;
            __builtin_amdgcn_global_load_lds((gas_t)src, (las_t)&sA[slot * 8], 16, 0, 0);
        }
        // stage B (PT): 32 rows x 8 chunks = 256 slots (threads 0..255)
        if (tid < 256) {
            const int row = tid >> 3;
            const int gc = sch ^ (row & 7);
            const ushort_t* src = Bm + ((size_t)(b * N_ + jb + row)) * N_ + k0 + gc * 8;
            __builtin_amdgcn_global_load_lds((gas_t)src, (las_t)&sB[tid * 8], 16, 0, 0);
        }
        __syncthreads();
#pragma unroll
        for (int ks = 0; ks < 2; ++ks) {
            bf16x8 af[2], bfg[2];
#pragma unroll
            for (int mt = 0; mt < 2; ++mt) {
                const int row = cw + mt * 16 + c16;
                af[mt] = *(const bf16x8*)&sA[row * 64 + (((ks * 4 + g) ^ (row & 7)) * 8)];
            }
#pragma unroll
            for (int nt = 0; nt < 2; ++nt) {
                const int row = nt * 16 + c16;
                bfg[nt] = *(const bf16x8*)&sB[row * 64 + (((ks * 4 + g) ^ (row & 7)) * 8)];
            }
#pragma unroll
            for (int mt = 0; mt < 2; ++mt)
#pragma unroll
                for (int nt = 0; nt < 2; ++nt)
                    acc[mt][nt] = __builtin_amdgcn_mfma_f32_16x16x32_bf16(af[mt], bfg[nt], acc[mt][nt], 0, 0, 0);
        }
        __syncthreads();
    }
    // epilogue: out = residual + acc, regular stores (no atomics)
#pragma unroll
    for (int mt = 0; mt < 2; ++mt)
#pragma unroll
        for (int r = 0; r < 4; ++r) {
            const int c = cw + mt * 16 + g * 4 + r;
            const size_t rowoff = ((size_t)(b * C_ + c)) * N_ + jb;
#pragma unroll
            for (int nt = 0; nt < 2; ++nt) {
                const int j = nt * 16 + c16;
                out[rowoff + j] = R[rowoff + j] + acc[mt][nt][r];
            }
        }
}

// ---------------------------------------------------------------------------
// Fallback Pass B (unchanged; used when ws_size < 161 MiB).
// ---------------------------------------------------------------------------
__global__ __launch_bounds__(512, 4)
void out_kernel(const ushort_t* __restrict__ Kt, const ushort_t* __restrict__ Qt,
                const ushort_t* __restrict__ V, const float* __restrict__ l,
                float* __restrict__ dout) {
    __shared__ ushort_t sQ[64][264];
    __shared__ ushort_t sP[64][264];
    const int tid = threadIdx.x;
    const int w = tid >> 6, lane = tid & 63, g = lane >> 4, c16 = lane & 15;
    const int b = blockIdx.z;
    const int jb = blockIdx.x * 64;
    const int ibase = blockIdx.y * 2048;
    {
        const int jl = tid >> 3, cp = (tid & 7) * 32;
        const ushort_t* src = Qt + ((size_t)(b * N_ + jb + jl)) * C_ + cp;
        uint4 a0 = *(const uint4*)(src);
        uint4 a1 = *(const uint4*)(src + 8);
        uint4 a2 = *(const uint4*)(src + 16);
        uint4 a3 = *(const uint4*)(src + 24);
        *(uint4*)&sQ[jl][cp + 0]  = a0;
        *(uint4*)&sQ[jl][cp + 8]  = a1;
        *(uint4*)&sQ[jl][cp + 16] = a2;
        *(uint4*)&sQ[jl][cp + 24] = a3;
    }
    f32x4 acc[2][4];
#pragma unroll
    for (int mt = 0; mt < 2; ++mt)
#pragma unroll
        for (int nt = 0; nt < 4; ++nt) acc[mt][nt] = (f32x4){0.f, 0.f, 0.f, 0.f};

    const int bw = w * 32;

    for (int ic = 0; ic < 8; ++ic) {
        const int i0 = ibase + ic * 256;
        float rv[2][4];
#pragma unroll
        for (int mt = 0; mt < 2; ++mt) {
            float4 lr = *(const float4*)(l + (size_t)b * N_ + i0 + bw + mt * 16 + g * 4);
            rv[mt][0] = __builtin_amdgcn_logf(lr.x);
            rv[mt][1] = __builtin_amdgcn_logf(lr.y);
            rv[mt][2] = __builtin_amdgcn_logf(lr.z);
            rv[mt][3] = __builtin_amdgcn_logf(lr.w);
        }
        __syncthreads();
        f32x4 sa[2][4];
#pragma unroll
        for (int mt = 0; mt < 2; ++mt)
#pragma unroll
            for (int nt = 0; nt < 4; ++nt) sa[mt][nt] = (f32x4){0.f, 0.f, 0.f, 0.f};
#pragma unroll
        for (int k = 0; k < 8; ++k) {
            bf16x8 av[2];
#pragma unroll
            for (int mt = 0; mt < 2; ++mt)
                av[mt] = ld_bf8(Kt + ((size_t)(b * N_ + i0 + bw + mt * 16 + c16)) * C_ + k * 32 + g * 8);
#pragma unroll
            for (int nt = 0; nt < 4; ++nt) {
                bf16x8 bv = *(const bf16x8*)&sQ[nt * 16 + c16][k * 32 + g * 8];
#pragma unroll
                for (int mt = 0; mt < 2; ++mt)
                    sa[mt][nt] = __builtin_amdgcn_mfma_f32_16x16x32_bf16(av[mt], bv, sa[mt][nt], 0, 0, 0);
            }
        }
#pragma unroll
        for (int mt = 0; mt < 2; ++mt)
#pragma unroll
            for (int nt = 0; nt < 4; ++nt) {
                const int j = nt * 16 + c16;
                unsigned p0 = f2bf(__builtin_amdgcn_exp2f(sa[mt][nt][0] - rv[mt][0]));
                unsigned p1 = f2bf(__builtin_amdgcn_exp2f(sa[mt][nt][1] - rv[mt][1]));
                unsigned p2 = f2bf(__builtin_amdgcn_exp2f(sa[mt][nt][2] - rv[mt][2]));
                unsigned p3 = f2bf(__builtin_amdgcn_exp2f(sa[mt][nt][3] - rv[mt][3]));
                uint2 pk; pk.x = p0 | (p1 << 16); pk.y = p2 | (p3 << 16);
                *(uint2*)&sP[j][bw + mt * 16 + g * 4] = pk;
            }
        __syncthreads();
#pragma unroll
        for (int ks = 0; ks < 8; ++ks) {
            bf16x8 va[2];
#pragma unroll
            for (int mt = 0; mt < 2; ++mt)
                va[mt] = ld_bf8(V + ((size_t)(b * C_ + bw + mt * 16 + c16)) * N_ + i0 + ks * 32 + g * 8);
#pragma unroll
            for (int nt = 0; nt < 4; ++nt) {
                bf16x8 pb = *(const bf16x8*)&sP[nt * 16 + c16][ks * 32 + g * 8];
#pragma unroll
                for (int mt = 0; mt < 2; ++mt)
                    acc[mt][nt] = __builtin_amdgcn_mfma_f32_16x16x32_bf16(va[mt], pb, acc[mt][nt], 0, 0, 0);
            }
        }
    }
#pragma unroll
    for (int mt = 0; mt < 2; ++mt)
#pragma unroll
        for (int nt = 0; nt < 4; ++nt)
#pragma unroll
            for (int r = 0; r < 4; ++r) {
                const int c = bw + mt * 16 + g * 4 + r;
                const int j = jb + nt * 16 + c16;
                atomicAdd(dout + ((size_t)b * C_ + c) * N_ + j, acc[mt][nt][r]);
            }
}

extern "C" void kernel_launch(void* const* d_in, const int* in_sizes, int n_in,
                              void* d_out, int out_size, void* d_ws, size_t ws_size,
                              hipStream_t stream) {
    const float* x_s2  = (const float*)d_in[0];
    const float* x_dem = (const float*)d_in[1];
    const float* Wq = (const float*)d_in[2];
    const float* bq = (const float*)d_in[3];
    const float* Wk = (const float*)d_in[4];
    const float* bk = (const float*)d_in[5];
    const float* Wv = (const float*)d_in[6];
    const float* bv = (const float*)d_in[7];
    float* out = (float*)d_out;

    const size_t MiB = 1024 * 1024;
    char* ws = (char*)d_ws;
    ushort_t* Qt = (ushort_t*)(ws);               // [B][N][C] bf16, 8 MiB
    ushort_t* Kt = (ushort_t*)(ws + 8  * MiB);    // [B][N][C] bf16, pre-scaled
    ushort_t* Vm = (ushort_t*)(ws + 16 * MiB);    // [B][C][N] bf16, 8 MiB
    ushort_t* Vs = (ushort_t*)(ws + 24 * MiB);    // [B][C][N] bf16, V/l, 8 MiB
    float*    lv = (float*)   (ws + 32 * MiB);    // [B][N] row sums, 64 KiB
    ushort_t* PT = (ushort_t*)(ws + 33 * MiB);    // [B][N(j)][N(i)] bf16, 128 MiB
    const bool bigws = ws_size >= 161 * MiB;

    hipMemsetAsync(lv, 0, (size_t)B_ * N_ * sizeof(float), stream);
    if (!bigws) {
        // fallback path needs residual-prefilled out for its atomics
        hipMemcpyAsync(out, x_s2, (size_t)B_ * C_ * N_ * sizeof(float),
                       hipMemcpyDeviceToDevice, stream);
    }

    proj_q_mfma<<<dim3(N_ / 128, C_ / 64, B_), 256, 0, stream>>>(x_s2, Wq, bq, Qt, C_, 1.0f);
    proj_kv_mfma<<<dim3(N_ / 128, C_ / 64, B_), 256, 0, stream>>>(x_dem, Wk, bk, Wv, bv, Kt, Vm);
    stats_kernel<<<dim3(N_ / 128, N_ / 128, B_), 256, 0, stream>>>(Kt, Qt, lv,
                                                                   bigws ? PT : (ushort_t*)nullptr);
    if (bigws) {
        scale_v_kernel<<<dim3(N_ / 2048, C_, B_), 256, 0, stream>>>(Vm, lv, Vs);
        gemm_out2_kernel<<<dim3(N_ / 32, B_), 512, 0, stream>>>(Vs, PT, x_s2, out);
    } else {
        out_kernel<<<dim3(N_ / 64, 2, B_), 512, 0, stream>>>(Kt, Qt, Vm, lv, out);
    }
}

// Round 12
// 219.263 us; speedup vs baseline: 1.1210x; 1.1210x over previous
//
#include <hip/hip_runtime.h>
#include <hip/hip_bf16.h>
#include <cstdint>

#define B_  4
#define N_  4096
#define C_  256
#define CD_ 64

typedef unsigned short ushort_t;
typedef unsigned char uchar_t;
typedef __bf16 bf16x8 __attribute__((ext_vector_type(8)));
typedef float f32x4 __attribute__((ext_vector_type(4)));

typedef const __attribute__((address_space(1))) void* gas_t;
typedef __attribute__((address_space(3))) void* las_t;

// (1/sqrt(256)) * log2(e): folded into K projection so S' = S_true * log2(e)
static constexpr float SCALE_LOG2E = 0.09016844005556021f;
// V' scale 2^13 (undone in gemm epilogue); PT exponent shift -3 cancels via l.
static constexpr float VSCALE = 8192.0f;
static constexpr float VSCALE_INV = 1.0f / 8192.0f;

__device__ __forceinline__ ushort_t f2bf(float x) {
    union { float f; unsigned u; } v; v.f = x;
    unsigned u = v.u;
    unsigned r = (u + 0x7fffu + ((u >> 16) & 1u)) >> 16;  // round-nearest-even
    return (ushort_t)r;
}

__device__ __forceinline__ bf16x8 ld_bf8(const ushort_t* p) {
    return *reinterpret_cast<const bf16x8*>(p);
}

// ---------------------------------------------------------------------------
// MFMA projection -> TRANSPOSED layout dst[b][n][o]  (proven R8)
// ---------------------------------------------------------------------------
__global__ __launch_bounds__(256, 4)
void proj_q_mfma(const float* __restrict__ X, const float* __restrict__ W,
                 const float* __restrict__ bias, ushort_t* __restrict__ dst,
                 int Cin, float outScale) {
    __shared__ ushort_t sX[128][72];   // [n][c] bf16
    __shared__ ushort_t sW[64][72];    // [o][c] bf16
    const int tid = threadIdx.x;
    const int lane = tid & 63, g = lane >> 4, c16 = lane & 15;
    const int w = tid >> 6, wi = w >> 1, wj = w & 1;   // n-half, o-half
    const int b = blockIdx.z, nb = blockIdx.x * 128, ob = blockIdx.y * 64;
    f32x4 acc[4][2];
#pragma unroll
    for (int nt = 0; nt < 4; ++nt)
#pragma unroll
        for (int ot = 0; ot < 2; ++ot) acc[nt][ot] = (f32x4){0.f, 0.f, 0.f, 0.f};

    const int cr = tid >> 5;
    const int n0 = (tid & 31) * 4;

    for (int k0 = 0; k0 < Cin; k0 += 64) {
#pragma unroll
        for (int p = 0; p < 8; ++p) {
            const int c = p * 8 + cr;
            float4 xv = *(const float4*)(X + ((size_t)b * Cin + k0 + c) * N_ + nb + n0);
            sX[n0 + 0][c] = f2bf(xv.x);
            sX[n0 + 1][c] = f2bf(xv.y);
            sX[n0 + 2][c] = f2bf(xv.z);
            sX[n0 + 3][c] = f2bf(xv.w);
        }
        {
            const int o = tid >> 2, cq = (tid & 3) * 16;
            const float* wsrc = W + (size_t)(ob + o) * Cin + k0 + cq;
            alignas(16) ushort_t tmp[16];
#pragma unroll
            for (int q = 0; q < 16; ++q) tmp[q] = f2bf(wsrc[q]);
            *(uint4*)&sW[o][cq]     = *(uint4*)&tmp[0];
            *(uint4*)&sW[o][cq + 8] = *(uint4*)&tmp[8];
        }
        __syncthreads();
#pragma unroll
        for (int ks = 0; ks < 2; ++ks) {
            bf16x8 af[4], bfr[2];
#pragma unroll
            for (int nt = 0; nt < 4; ++nt)
                af[nt] = *(const bf16x8*)&sX[wi * 64 + nt * 16 + c16][ks * 32 + g * 8];
#pragma unroll
            for (int ot = 0; ot < 2; ++ot)
                bfr[ot] = *(const bf16x8*)&sW[wj * 32 + ot * 16 + c16][ks * 32 + g * 8];
#pragma unroll
            for (int nt = 0; nt < 4; ++nt)
#pragma unroll
                for (int ot = 0; ot < 2; ++ot)
                    acc[nt][ot] = __builtin_amdgcn_mfma_f32_16x16x32_bf16(af[nt], bfr[ot], acc[nt][ot], 0, 0, 0);
        }
        __syncthreads();
    }
#pragma unroll
    for (int ot = 0; ot < 2; ++ot) {
        const int o = ob + wj * 32 + ot * 16 + c16;
        const float bia = bias[o];
#pragma unroll
        for (int nt = 0; nt < 4; ++nt) {
#pragma unroll
            for (int r = 0; r < 4; ++r) {
                const int n = nb + wi * 64 + nt * 16 + g * 4 + r;
                dst[((size_t)b * N_ + n) * C_ + o] = f2bf((acc[nt][ot][r] + bia) * outScale);
            }
        }
    }
}

// ---------------------------------------------------------------------------
// Fused K+V MFMA projection from x_dem (proven R8)
// ---------------------------------------------------------------------------
__global__ __launch_bounds__(256, 4)
void proj_kv_mfma(const float* __restrict__ X, const float* __restrict__ Wk,
                  const float* __restrict__ bk, const float* __restrict__ Wv,
                  const float* __restrict__ bv, ushort_t* __restrict__ Kt,
                  ushort_t* __restrict__ Vm) {
    __shared__ ushort_t sX[128][72];   // [n][c]
    __shared__ ushort_t sWk[64][72];   // [o][c]
    __shared__ ushort_t sWv[64][72];
    const int tid = threadIdx.x;
    const int lane = tid & 63, g = lane >> 4, c16 = lane & 15;
    const int w = tid >> 6;
    const int b = blockIdx.z, nb = blockIdx.x * 128, ob = blockIdx.y * 64;

    {
        const int cr = tid >> 5, n0 = (tid & 31) * 4;
#pragma unroll
        for (int p = 0; p < 8; ++p) {
            const int c = p * 8 + cr;
            float4 xv = *(const float4*)(X + ((size_t)b * CD_ + c) * N_ + nb + n0);
            sX[n0 + 0][c] = f2bf(xv.x);
            sX[n0 + 1][c] = f2bf(xv.y);
            sX[n0 + 2][c] = f2bf(xv.z);
            sX[n0 + 3][c] = f2bf(xv.w);
        }
        const int o = tid >> 2, cq = (tid & 3) * 16;
        alignas(16) ushort_t tk[16], tv[16];
        const float* ksrc = Wk + (size_t)(ob + o) * CD_ + cq;
        const float* vsrc = Wv + (size_t)(ob + o) * CD_ + cq;
#pragma unroll
        for (int q = 0; q < 16; ++q) { tk[q] = f2bf(ksrc[q]); tv[q] = f2bf(vsrc[q]); }
        *(uint4*)&sWk[o][cq]     = *(uint4*)&tk[0];
        *(uint4*)&sWk[o][cq + 8] = *(uint4*)&tk[8];
        *(uint4*)&sWv[o][cq]     = *(uint4*)&tv[0];
        *(uint4*)&sWv[o][cq + 8] = *(uint4*)&tv[8];
    }
    __syncthreads();
    // ---- K-part ----
    {
        const int wi = w >> 1, wj = w & 1;
        f32x4 acc[4][2];
#pragma unroll
        for (int nt = 0; nt < 4; ++nt)
#pragma unroll
            for (int ot = 0; ot < 2; ++ot) acc[nt][ot] = (f32x4){0.f, 0.f, 0.f, 0.f};
#pragma unroll
        for (int ks = 0; ks < 2; ++ks) {
            bf16x8 af[4], bfr[2];
#pragma unroll
            for (int nt = 0; nt < 4; ++nt)
                af[nt] = *(const bf16x8*)&sX[wi * 64 + nt * 16 + c16][ks * 32 + g * 8];
#pragma unroll
            for (int ot = 0; ot < 2; ++ot)
                bfr[ot] = *(const bf16x8*)&sWk[wj * 32 + ot * 16 + c16][ks * 32 + g * 8];
#pragma unroll
            for (int nt = 0; nt < 4; ++nt)
#pragma unroll
                for (int ot = 0; ot < 2; ++ot)
                    acc[nt][ot] = __builtin_amdgcn_mfma_f32_16x16x32_bf16(af[nt], bfr[ot], acc[nt][ot], 0, 0, 0);
        }
#pragma unroll
        for (int ot = 0; ot < 2; ++ot) {
            const int o = ob + wj * 32 + ot * 16 + c16;
            const float bia = bk[o];
#pragma unroll
            for (int nt = 0; nt < 4; ++nt)
#pragma unroll
                for (int r = 0; r < 4; ++r) {
                    const int n = nb + wi * 64 + nt * 16 + g * 4 + r;
                    Kt[((size_t)b * N_ + n) * C_ + o] = f2bf((acc[nt][ot][r] + bia) * SCALE_LOG2E);
                }
        }
    }
    // ---- V-part ----
    {
        const int ow = w & 1, nw = w >> 1;
        f32x4 acc[2][4];
#pragma unroll
        for (int mt = 0; mt < 2; ++mt)
#pragma unroll
            for (int nt = 0; nt < 4; ++nt) acc[mt][nt] = (f32x4){0.f, 0.f, 0.f, 0.f};
#pragma unroll
        for (int ks = 0; ks < 2; ++ks) {
            bf16x8 af[2], bfr[4];
#pragma unroll
            for (int mt = 0; mt < 2; ++mt)
                af[mt] = *(const bf16x8*)&sWv[ow * 32 + mt * 16 + c16][ks * 32 + g * 8];
#pragma unroll
            for (int nt = 0; nt < 4; ++nt)
                bfr[nt] = *(const bf16x8*)&sX[nw * 64 + nt * 16 + c16][ks * 32 + g * 8];
#pragma unroll
            for (int mt = 0; mt < 2; ++mt)
#pragma unroll
                for (int nt = 0; nt < 4; ++nt)
                    acc[mt][nt] = __builtin_amdgcn_mfma_f32_16x16x32_bf16(af[mt], bfr[nt], acc[mt][nt], 0, 0, 0);
        }
#pragma unroll
        for (int mt = 0; mt < 2; ++mt) {
            const float4 bi4 = *(const float4*)(bv + ob + ow * 32 + mt * 16 + g * 4);
            const float bia[4] = {bi4.x, bi4.y, bi4.z, bi4.w};
#pragma unroll
            for (int nt = 0; nt < 4; ++nt) {
                const int n = nb + nw * 64 + nt * 16 + c16;
#pragma unroll
                for (int r = 0; r < 4; ++r) {
                    const int o = ob + ow * 32 + mt * 16 + g * 4 + r;
                    Vm[((size_t)b * C_ + o) * N_ + n] = f2bf(acc[mt][nt][r] + bia[r]);
                }
            }
        }
    }
}

// ---------------------------------------------------------------------------
// Pass A (R6 structure, (256,4)).  R12: PT stored as fp8 e4m3 of
// exp2(S'-3) — shift keeps range in [~1e-3, 37] (sat limit 448); the -3
// cancels because l accumulates the SHIFTED sums and 1/l folds into V'.
// PT epilogue: cvt_pk_fp8 -> LDS tile [128][144B] -> full-128B-line streamout.
// Fallback path (PT==null): shift 0, l unshifted (out_kernel unchanged).
// ---------------------------------------------------------------------------
__global__ __launch_bounds__(256, 4)
void stats_kernel(const ushort_t* __restrict__ Kt, const ushort_t* __restrict__ Qt,
                  float* __restrict__ l, uchar_t* __restrict__ PT8) {
    __shared__ ushort_t smem[16384];   // staging 32 KB; epilogue sp8 uses 18432 B
    uchar_t* sp8 = (uchar_t*)smem;     // [128][144] fp8 tile (+16B pad/row)
    const int tid = threadIdx.x;
    const int lane = tid & 63, g = lane >> 4, c16 = lane & 15;
    const int w = tid >> 6, wi = w >> 1, wj = w & 1;
    const int b = blockIdx.z;
    const int ib = blockIdx.y * 128, jb = blockIdx.x * 128;
    f32x4 acc[4][4];
#pragma unroll
    for (int mt = 0; mt < 4; ++mt)
#pragma unroll
        for (int nt = 0; nt < 4; ++nt) acc[mt][nt] = (f32x4){0.f, 0.f, 0.f, 0.f};

    const int srow = tid >> 3;
    const int sc4 = tid & 7;

    for (int k0 = 0; k0 < 256; k0 += 64) {
#pragma unroll
        for (int q = 0; q < 4; ++q) {
            const int row = q * 32 + srow;
            const int gc = sc4 ^ (row & 7);
            const ushort_t* srcA = Kt + ((size_t)(b * N_ + ib + row)) * C_ + k0 + gc * 8;
            const ushort_t* srcB = Qt + ((size_t)(b * N_ + jb + row)) * C_ + k0 + gc * 8;
            __builtin_amdgcn_global_load_lds((gas_t)srcA, (las_t)&smem[(q * 256 + tid) * 8], 16, 0, 0);
            __builtin_amdgcn_global_load_lds((gas_t)srcB, (las_t)&smem[8192 + (q * 256 + tid) * 8], 16, 0, 0);
        }
        __syncthreads();
#pragma unroll
        for (int ks = 0; ks < 2; ++ks) {
            bf16x8 af[4], bf[4];
#pragma unroll
            for (int mt = 0; mt < 4; ++mt) {
                const int row = wi * 64 + mt * 16 + c16;
                af[mt] = *(const bf16x8*)&smem[row * 64 + (((ks * 4 + g) ^ (row & 7)) * 8)];
            }
#pragma unroll
            for (int nt = 0; nt < 4; ++nt) {
                const int row = wj * 64 + nt * 16 + c16;
                bf[nt] = *(const bf16x8*)&smem[8192 + row * 64 + (((ks * 4 + g) ^ (row & 7)) * 8)];
            }
#pragma unroll
            for (int mt = 0; mt < 4; ++mt)
#pragma unroll
                for (int nt = 0; nt < 4; ++nt)
                    acc[mt][nt] = __builtin_amdgcn_mfma_f32_16x16x32_bf16(af[mt], bf[nt], acc[mt][nt], 0, 0, 0);
        }
        __syncthreads();
    }
    const float sh = (PT8 != nullptr) ? 3.0f : 0.0f;
#pragma unroll
    for (int mt = 0; mt < 4; ++mt) {
        float rs[4] = {0.f, 0.f, 0.f, 0.f};
#pragma unroll
        for (int nt = 0; nt < 4; ++nt) {
            float e0 = __builtin_amdgcn_exp2f(acc[mt][nt][0] - sh);
            float e1 = __builtin_amdgcn_exp2f(acc[mt][nt][1] - sh);
            float e2 = __builtin_amdgcn_exp2f(acc[mt][nt][2] - sh);
            float e3 = __builtin_amdgcn_exp2f(acc[mt][nt][3] - sh);
            rs[0] += e0; rs[1] += e1; rs[2] += e2; rs[3] += e3;
            if (PT8 != nullptr) {
                int pk = __builtin_amdgcn_cvt_pk_fp8_f32(e0, e1, 0, false);
                pk = __builtin_amdgcn_cvt_pk_fp8_f32(e2, e3, pk, true);
                const int jl = wj * 64 + nt * 16 + c16;
                const int il = wi * 64 + mt * 16 + g * 4;
                *(int*)&sp8[jl * 144 + il] = pk;
            }
        }
#pragma unroll
        for (int r = 0; r < 4; ++r) {
            float s = rs[r];
            s += __shfl_xor(s, 1, 64);
            s += __shfl_xor(s, 2, 64);
            s += __shfl_xor(s, 4, 64);
            s += __shfl_xor(s, 8, 64);
            if (c16 == 0)
                atomicAdd(l + (size_t)b * N_ + ib + wi * 64 + mt * 16 + g * 4 + r, s);
        }
    }
    if (PT8 != nullptr) {
        __syncthreads();
        // stream out: 128 rows x 128 B (fp8); every 128-B HBM line fully written
        const int chb = tid & 7;     // 16B chunk within row
        const int rb = tid >> 3;     // 32 rows per pass
#pragma unroll
        for (int r = 0; r < 4; ++r) {
            const int jl = r * 32 + rb;
            uint4 v = *(const uint4*)&sp8[jl * 144 + chb * 16];
            *(uint4*)(PT8 + ((size_t)(b * N_ + jb + jl)) * N_ + ib + chb * 16) = v;
        }
    }
}

// ---------------------------------------------------------------------------
// V'' = V * 2^13 * rcp(l') -> fp8 e4m3.  grid (N/2048, C, B), block 256.
// ---------------------------------------------------------------------------
__global__ void scale_v_kernel(const ushort_t* __restrict__ Vm, const float* __restrict__ l,
                               uchar_t* __restrict__ Vs) {
    const int i = (blockIdx.x * 256 + threadIdx.x) * 8;
    const int c = blockIdx.y, b = blockIdx.z;
    float4 l0 = *(const float4*)(l + (size_t)b * N_ + i);
    float4 l1 = *(const float4*)(l + (size_t)b * N_ + i + 4);
    float r[8] = {__builtin_amdgcn_rcpf(l0.x), __builtin_amdgcn_rcpf(l0.y),
                  __builtin_amdgcn_rcpf(l0.z), __builtin_amdgcn_rcpf(l0.w),
                  __builtin_amdgcn_rcpf(l1.x), __builtin_amdgcn_rcpf(l1.y),
                  __builtin_amdgcn_rcpf(l1.z), __builtin_amdgcn_rcpf(l1.w)};
    const size_t off = ((size_t)(b * C_ + c)) * N_ + i;
    uint4 v = *(const uint4*)(Vm + off);
    unsigned vw[4] = {v.x, v.y, v.z, v.w};
    float f[8];
#pragma unroll
    for (int q = 0; q < 4; ++q) {
        union { unsigned u; float fl; } lo, hi;
        lo.u = (vw[q] & 0xffffu) << 16;
        hi.u = vw[q] & 0xffff0000u;
        f[q * 2 + 0] = lo.fl * r[q * 2 + 0] * VSCALE;
        f[q * 2 + 1] = hi.fl * r[q * 2 + 1] * VSCALE;
    }
    int d0 = __builtin_amdgcn_cvt_pk_fp8_f32(f[0], f[1], 0, false);
    d0 = __builtin_amdgcn_cvt_pk_fp8_f32(f[2], f[3], d0, true);
    int d1 = __builtin_amdgcn_cvt_pk_fp8_f32(f[4], f[5], 0, false);
    d1 = __builtin_amdgcn_cvt_pk_fp8_f32(f[6], f[7], d1, true);
    uint2 o; o.x = (unsigned)d0; o.y = (unsigned)d1;
    *(uint2*)(Vs + off) = o;
}

// ---------------------------------------------------------------------------
// Pass B v8: fp8 single-K GEMM, no atomics, fused residual.
// R12: A=V''(fp8), B=PT(fp8), mfma_f32_16x16x32_fp8_fp8 (bf16 rate, 8B i64
// frags).  BK=128 elements = 128 B/row: same staging byte-layout as R11 but
// HALF the iterations/barriers and half the HBM bytes.  Epilogue undoes the
// 2^13 V-scale.  grid (128 j-tiles, B), 2 blocks/CU.
// ---------------------------------------------------------------------------
__global__ __launch_bounds__(512, 4)
void gemm_out2_kernel(const uchar_t* __restrict__ A /*Vs fp8 [B][C][N]*/,
                      const uchar_t* __restrict__ Bm /*PT fp8 [B][N][N]*/,
                      const float* __restrict__ R /*x_s2 as [B][C][N]*/,
                      float* __restrict__ out) {
    __shared__ uchar_t sA[256 * 128];   // 32 KB: rows c, 8 swizzled 16B chunks
    __shared__ uchar_t sB[32 * 128];    //  4 KB: rows j
    const int tid = threadIdx.x;
    const int lane = tid & 63, g = lane >> 4, c16 = lane & 15;
    const int w = tid >> 6;
    const int cw = w * 32;              // wave's 32-c band
    const int b = blockIdx.y;
    const int jb = blockIdx.x * 32;

    f32x4 acc[2][2];
#pragma unroll
    for (int mt = 0; mt < 2; ++mt)
#pragma unroll
        for (int nt = 0; nt < 2; ++nt) acc[mt][nt] = (f32x4){0.f, 0.f, 0.f, 0.f};

    const int sch = tid & 7;          // chunk slot within row

    for (int k0 = 0; k0 < 4096; k0 += 128) {
        // stage A (Vs): 256 rows x 8 chunks = 2048 slots, 4 passes
#pragma unroll
        for (int q = 0; q < 4; ++q) {
            const int slot = q * 512 + tid;
            const int row = slot >> 3;
            const int gc = sch ^ (row & 7);
            const uchar_t* src = A + ((size_t)(b * C_ + row)) * N_ + k0 + gc * 16;
            __builtin_amdgcn_global_load_lds((gas_t)src, (las_t)&sA[slot * 16], 16, 0, 0);
        }
        // stage B (PT): 32 rows x 8 chunks = 256 slots (threads 0..255)
        if (tid < 256) {
            const int row = tid >> 3;
            const int gc = sch ^ (row & 7);
            const uchar_t* src = Bm + ((size_t)(b * N_ + jb + row)) * N_ + k0 + gc * 16;
            __builtin_amdgcn_global_load_lds((gas_t)src, (las_t)&sB[tid * 16], 16, 0, 0);
        }
        __syncthreads();
#pragma unroll
        for (int ks = 0; ks < 4; ++ks) {    // 4 x K=32
            const int lc = ks * 2 + (g >> 1);       // logical 16B chunk
            const int bo = (g & 1) * 8;             // byte within chunk
            long af[2], bfg[2];
#pragma unroll
            for (int mt = 0; mt < 2; ++mt) {
                const int row = cw + mt * 16 + c16;
                af[mt] = *(const long*)&sA[row * 128 + ((lc ^ (row & 7)) * 16) + bo];
            }
#pragma unroll
            for (int nt = 0; nt < 2; ++nt) {
                const int row = nt * 16 + c16;
                bfg[nt] = *(const long*)&sB[row * 128 + ((lc ^ (row & 7)) * 16) + bo];
            }
#pragma unroll
            for (int mt = 0; mt < 2; ++mt)
#pragma unroll
                for (int nt = 0; nt < 2; ++nt)
                    acc[mt][nt] = __builtin_amdgcn_mfma_f32_16x16x32_fp8_fp8(af[mt], bfg[nt], acc[mt][nt], 0, 0, 0);
        }
        __syncthreads();
    }
    // epilogue: out = residual + acc * 2^-13, regular stores (no atomics)
#pragma unroll
    for (int mt = 0; mt < 2; ++mt)
#pragma unroll
        for (int r = 0; r < 4; ++r) {
            const int c = cw + mt * 16 + g * 4 + r;
            const size_t rowoff = ((size_t)(b * C_ + c)) * N_ + jb;
#pragma unroll
            for (int nt = 0; nt < 2; ++nt) {
                const int j = nt * 16 + c16;
                out[rowoff + j] = R[rowoff + j] + acc[mt][nt][r] * VSCALE_INV;
            }
        }
}

// ---------------------------------------------------------------------------
// Fallback Pass B (unchanged; used when ws small).  Needs bf16 V (Vm) and
// UNSHIFTED l (stats uses sh=0 when PT==null).
// ---------------------------------------------------------------------------
__global__ __launch_bounds__(512, 4)
void out_kernel(const ushort_t* __restrict__ Kt, const ushort_t* __restrict__ Qt,
                const ushort_t* __restrict__ V, const float* __restrict__ l,
                float* __restrict__ dout) {
    __shared__ ushort_t sQ[64][264];
    __shared__ ushort_t sP[64][264];
    const int tid = threadIdx.x;
    const int w = tid >> 6, lane = tid & 63, g = lane >> 4, c16 = lane & 15;
    const int b = blockIdx.z;
    const int jb = blockIdx.x * 64;
    const int ibase = blockIdx.y * 2048;
    {
        const int jl = tid >> 3, cp = (tid & 7) * 32;
        const ushort_t* src = Qt + ((size_t)(b * N_ + jb + jl)) * C_ + cp;
        uint4 a0 = *(const uint4*)(src);
        uint4 a1 = *(const uint4*)(src + 8);
        uint4 a2 = *(const uint4*)(src + 16);
        uint4 a3 = *(const uint4*)(src + 24);
        *(uint4*)&sQ[jl][cp + 0]  = a0;
        *(uint4*)&sQ[jl][cp + 8]  = a1;
        *(uint4*)&sQ[jl][cp + 16] = a2;
        *(uint4*)&sQ[jl][cp + 24] = a3;
    }
    f32x4 acc[2][4];
#pragma unroll
    for (int mt = 0; mt < 2; ++mt)
#pragma unroll
        for (int nt = 0; nt < 4; ++nt) acc[mt][nt] = (f32x4){0.f, 0.f, 0.f, 0.f};

    const int bw = w * 32;

    for (int ic = 0; ic < 8; ++ic) {
        const int i0 = ibase + ic * 256;
        float rv[2][4];
#pragma unroll
        for (int mt = 0; mt < 2; ++mt) {
            float4 lr = *(const float4*)(l + (size_t)b * N_ + i0 + bw + mt * 16 + g * 4);
            rv[mt][0] = __builtin_amdgcn_logf(lr.x);
            rv[mt][1] = __builtin_amdgcn_logf(lr.y);
            rv[mt][2] = __builtin_amdgcn_logf(lr.z);
            rv[mt][3] = __builtin_amdgcn_logf(lr.w);
        }
        __syncthreads();
        f32x4 sa[2][4];
#pragma unroll
        for (int mt = 0; mt < 2; ++mt)
#pragma unroll
            for (int nt = 0; nt < 4; ++nt) sa[mt][nt] = (f32x4){0.f, 0.f, 0.f, 0.f};
#pragma unroll
        for (int k = 0; k < 8; ++k) {
            bf16x8 av[2];
#pragma unroll
            for (int mt = 0; mt < 2; ++mt)
                av[mt] = ld_bf8(Kt + ((size_t)(b * N_ + i0 + bw + mt * 16 + c16)) * C_ + k * 32 + g * 8);
#pragma unroll
            for (int nt = 0; nt < 4; ++nt) {
                bf16x8 bv = *(const bf16x8*)&sQ[nt * 16 + c16][k * 32 + g * 8];
#pragma unroll
                for (int mt = 0; mt < 2; ++mt)
                    sa[mt][nt] = __builtin_amdgcn_mfma_f32_16x16x32_bf16(av[mt], bv, sa[mt][nt], 0, 0, 0);
            }
        }
#pragma unroll
        for (int mt = 0; mt < 2; ++mt)
#pragma unroll
            for (int nt = 0; nt < 4; ++nt) {
                const int j = nt * 16 + c16;
                unsigned p0 = f2bf(__builtin_amdgcn_exp2f(sa[mt][nt][0] - rv[mt][0]));
                unsigned p1 = f2bf(__builtin_amdgcn_exp2f(sa[mt][nt][1] - rv[mt][1]));
                unsigned p2 = f2bf(__builtin_amdgcn_exp2f(sa[mt][nt][2] - rv[mt][2]));
                unsigned p3 = f2bf(__builtin_amdgcn_exp2f(sa[mt][nt][3] - rv[mt][3]));
                uint2 pk; pk.x = p0 | (p1 << 16); pk.y = p2 | (p3 << 16);
                *(uint2*)&sP[j][bw + mt * 16 + g * 4] = pk;
            }
        __syncthreads();
#pragma unroll
        for (int ks = 0; ks < 8; ++ks) {
            bf16x8 va[2];
#pragma unroll
            for (int mt = 0; mt < 2; ++mt)
                va[mt] = ld_bf8(V + ((size_t)(b * C_ + bw + mt * 16 + c16)) * N_ + i0 + ks * 32 + g * 8);
#pragma unroll
            for (int nt = 0; nt < 4; ++nt) {
                bf16x8 pb = *(const bf16x8*)&sP[nt * 16 + c16][ks * 32 + g * 8];
#pragma unroll
                for (int mt = 0; mt < 2; ++mt)
                    acc[mt][nt] = __builtin_amdgcn_mfma_f32_16x16x32_bf16(va[mt], pb, acc[mt][nt], 0, 0, 0);
            }
        }
    }
#pragma unroll
    for (int mt = 0; mt < 2; ++mt)
#pragma unroll
        for (int nt = 0; nt < 4; ++nt)
#pragma unroll
            for (int r = 0; r < 4; ++r) {
                const int c = bw + mt * 16 + g * 4 + r;
                const int j = jb + nt * 16 + c16;
                atomicAdd(dout + ((size_t)b * C_ + c) * N_ + j, acc[mt][nt][r]);
            }
}

extern "C" void kernel_launch(void* const* d_in, const int* in_sizes, int n_in,
                              void* d_out, int out_size, void* d_ws, size_t ws_size,
                              hipStream_t stream) {
    const float* x_s2  = (const float*)d_in[0];
    const float* x_dem = (const float*)d_in[1];
    const float* Wq = (const float*)d_in[2];
    const float* bq = (const float*)d_in[3];
    const float* Wk = (const float*)d_in[4];
    const float* bk = (const float*)d_in[5];
    const float* Wv = (const float*)d_in[6];
    const float* bv = (const float*)d_in[7];
    float* out = (float*)d_out;

    const size_t MiB = 1024 * 1024;
    char* ws = (char*)d_ws;
    ushort_t* Qt = (ushort_t*)(ws);               // [B][N][C] bf16, 8 MiB
    ushort_t* Kt = (ushort_t*)(ws + 8  * MiB);    // [B][N][C] bf16, pre-scaled
    ushort_t* Vm = (ushort_t*)(ws + 16 * MiB);    // [B][C][N] bf16, 8 MiB
    uchar_t*  Vs = (uchar_t*) (ws + 24 * MiB);    // [B][C][N] fp8 V'', 4 MiB
    float*    lv = (float*)   (ws + 28 * MiB);    // [B][N] row sums, 64 KiB
    uchar_t*  PT = (uchar_t*) (ws + 29 * MiB);    // [B][N(j)][N(i)] fp8, 64 MiB
    const bool bigws = ws_size >= 93 * MiB;

    hipMemsetAsync(lv, 0, (size_t)B_ * N_ * sizeof(float), stream);
    if (!bigws) {
        // fallback path needs residual-prefilled out for its atomics
        hipMemcpyAsync(out, x_s2, (size_t)B_ * C_ * N_ * sizeof(float),
                       hipMemcpyDeviceToDevice, stream);
    }

    proj_q_mfma<<<dim3(N_ / 128, C_ / 64, B_), 256, 0, stream>>>(x_s2, Wq, bq, Qt, C_, 1.0f);
    proj_kv_mfma<<<dim3(N_ / 128, C_ / 64, B_), 256, 0, stream>>>(x_dem, Wk, bk, Wv, bv, Kt, Vm);
    stats_kernel<<<dim3(N_ / 128, N_ / 128, B_), 256, 0, stream>>>(Kt, Qt, lv,
                                                                   bigws ? PT : (uchar_t*)nullptr);
    if (bigws) {
        scale_v_kernel<<<dim3(N_ / 2048, C_, B_), 256, 0, stream>>>(Vm, lv, Vs);
        gemm_out2_kernel<<<dim3(N_ / 32, B_), 512, 0, stream>>>(Vs, PT, x_s2, out);
    } else {
        out_kernel<<<dim3(N_ / 64, 2, B_), 512, 0, stream>>>(Kt, Qt, Vm, lv, out);
    }
}